// Round 10
// baseline (82.844 us; speedup 1.0000x reference)
//
#include <hip/hip_runtime.h>

// 2-layer dense GAT, B=32, N=1024, all fp32. L1: H=3,F=4,O=2 -> ws. L2: H=1,F=6,O=4 -> out.
//
// Round-10 (on top of r9's scale-invariant factorization + packed math):
//  * b-minor block ordering: b = bid & 31 => all blocks touching batch b land
//    on XCD b%8 (round-robin dispatch). L1 writes h1[b] into that XCD's L2;
//    L2 blocks for batch b read it locally. Perf-only heuristic.
//  * wave-local reduction: lane = (slice<<2)|rowgroup, all 16 slices in one
//    wave; slice-reduce = 4x shfl_xor(1,2,4,8). Removes sredu LDS, the 2nd
//    __syncthreads, and the epilogue re-read pass. Epilogue in registers on
//    sl==0 lanes, vector stores (float2 for O=2, float4 for O=4).
//  * w = max(rho*E1[m], E2[m]), rho = e^{0.8 sn}; E1=e^{dm}, E2=e^{0.2dm}.
//    Softmax ratio cancels the scale; overflow-safe for this data range.

#define GAT_ALPHA 0.2f
#define LOG2E 1.44269504088896f

typedef float v2f __attribute__((ext_vector_type(2)));

template <int F, int O, int H, int RPB, int MINW>
__global__ __launch_bounds__(256, MINW) void gat_layer_kernel(
    const float* __restrict__ x,            // (B, N, F)
    const float* __restrict__ Wt,           // (H, F, O)
    const float* __restrict__ at,           // (H, 2*O)
    float* __restrict__ out)                // (B, N, H*O)
{
    constexpr int N = 1024, NT = 256;
    constexpr int NP = N / 2;            // m-pairs
    constexpr int WROWS = RPB / 4;       // rows per wave (16 or 8)
    constexpr int R = WROWS / 4;         // rows per lane (4 or 2)
    constexpr int CHUNKS = N / RPB;

    const int bid   = blockIdx.x;
    const int b     = bid & 31;          // b-minor -> XCD = b%8 locality
    const int rest  = bid >> 5;
    const int h     = rest % H;
    const int chunk = rest / H;
    const int tid   = threadIdx.x;
    const int wv    = tid >> 6, l = tid & 63;
    const int sl    = l >> 2;            // m-slice 0..15 (all in-wave)
    const int rg    = l & 3;             // row group in wave 0..3

    // Per-head weights (block-uniform -> scalar loads)
    float Wl[F][O];
#pragma unroll
    for (int f = 0; f < F; ++f)
#pragma unroll
        for (int o = 0; o < O; ++o) Wl[f][o] = Wt[(h * F + f) * O + o];
    float asrc[O], adst[O];
#pragma unroll
    for (int o = 0; o < O; ++o) {
        asrc[o] = at[h * 2 * O + o];
        adst[o] = at[h * 2 * O + O + o];
    }

    __shared__ float4 sE[NP];                  // (E1lo,E1hi,E2lo,E2hi), E=e^{d}, e^{.2d}
    __shared__ float4 sW01[NP];                // (W0lo,W0hi,W1lo,W1hi)
    __shared__ float4 sW23[(O > 2) ? NP : 1];  // (W2lo,W2hi,W3lo,W3hi)

    // ---- Stage: per pair q compute Wh, d, exp factors ----
    const float* xb = x + (size_t)b * N * F;
#pragma unroll
    for (int qq = 0; qq < NP / NT; ++qq) {
        const int q = qq * NT + tid;
        float xv[2][F];
        if constexpr (F == 4) {
            const float4 va = ((const float4*)xb)[2 * q];
            const float4 vb = ((const float4*)xb)[2 * q + 1];
            xv[0][0] = va.x; xv[0][1] = va.y; xv[0][2] = va.z; xv[0][3] = va.w;
            xv[1][0] = vb.x; xv[1][1] = vb.y; xv[1][2] = vb.z; xv[1][3] = vb.w;
        } else {  // F == 6: 2 rows = 48 B = f4+f2 | f2+f4
            const float4* x4 = (const float4*)xb;
            const float2* x2 = (const float2*)xb;
            const float4 fa = x4[3 * q];
            const float2 fb = x2[6 * q + 2];
            const float2 fc = x2[6 * q + 3];
            const float4 fd = x4[3 * q + 2];
            xv[0][0] = fa.x; xv[0][1] = fa.y; xv[0][2] = fa.z; xv[0][3] = fa.w;
            xv[0][4] = fb.x; xv[0][5] = fb.y;
            xv[1][0] = fc.x; xv[1][1] = fc.y;
            xv[1][2] = fd.x; xv[1][3] = fd.y; xv[1][4] = fd.z; xv[1][5] = fd.w;
        }
        float wh[2][O], d[2];
#pragma unroll
        for (int p = 0; p < 2; ++p) {
            d[p] = 0.0f;
#pragma unroll
            for (int o = 0; o < O; ++o) {
                float acc = 0.0f;
#pragma unroll
                for (int f = 0; f < F; ++f) acc += xv[p][f] * Wl[f][o];
                wh[p][o] = acc; d[p] += acc * adst[o];
            }
        }
        const float t0 = d[0] * LOG2E, t1 = d[1] * LOG2E;
        sE[q] = make_float4(__builtin_amdgcn_exp2f(t0),
                            __builtin_amdgcn_exp2f(t1),
                            __builtin_amdgcn_exp2f(GAT_ALPHA * t0),
                            __builtin_amdgcn_exp2f(GAT_ALPHA * t1));
        sW01[q] = make_float4(wh[0][0], wh[1][0], wh[0][1], wh[1][1]);
        if constexpr (O > 2)
            sW23[q] = make_float4(wh[0][2], wh[1][2], wh[0][3], wh[1][3]);
    }
    __syncthreads();                           // single barrier

    // ---- Per-row rho = e^{0.8 sn}; lane rows: base + rg + 4*j ----
    const int rowbase = chunk * RPB + wv * WROWS;
    float rho[R];
#pragma unroll
    for (int j = 0; j < R; ++j) {
        const int row = rowbase + rg + 4 * j;
        const int qr = row >> 1, cp = row & 1;
        const float4 w01 = sW01[qr];
        float sn = (cp ? w01.y : w01.x) * asrc[0] + (cp ? w01.w : w01.z) * asrc[1];
        if constexpr (O > 2) {
            const float4 w23 = sW23[qr];
            sn += (cp ? w23.y : w23.x) * asrc[2] + (cp ? w23.w : w23.z) * asrc[3];
        }
        rho[j] = __builtin_amdgcn_exp2f(0.8f * LOG2E * sn);
    }

    // ---- Inner loop: packed m-pairs over own slice ----
    v2f den[R], num[R][O];
#pragma unroll
    for (int j = 0; j < R; ++j) {
        den[j] = (v2f)(0.0f);
#pragma unroll
        for (int o = 0; o < O; ++o) num[j][o] = (v2f)(0.0f);
    }

#pragma unroll 4
    for (int p = 0; p < NP / 16; ++p) {
        const int q = p * 16 + sl;             // 16 consecutive f4 per 16 lanes: 2-way, free
        const float4 e4 = sE[q];
        const float4 w4 = sW01[q];
        const v2f E1 = {e4.x, e4.y}, E2 = {e4.z, e4.w};
        const v2f W0 = {w4.x, w4.y}, W1v = {w4.z, w4.w};
        v2f W2v, W3v;
        if constexpr (O > 2) {
            const float4 w4b = sW23[q];
            W2v = (v2f){w4b.x, w4b.y}; W3v = (v2f){w4b.z, w4b.w};
        }
#pragma unroll
        for (int j = 0; j < R; ++j) {
            const v2f t = rho[j] * E1;         // v_pk_mul_f32
            v2f w;
            w.x = fmaxf(t.x, E2.x);            // v_max_f32 x2
            w.y = fmaxf(t.y, E2.y);
            den[j] += w;                       // v_pk_add_f32
            num[j][0] += w * W0;               // v_pk_fma_f32
            num[j][1] += w * W1v;
            if constexpr (O > 2) {
                num[j][2] += w * W2v;
                num[j][3] += w * W3v;
            }
        }
    }

    // ---- In-wave slice reduction (16 slices = lane bits 2..5) ----
#pragma unroll
    for (int j = 0; j < R; ++j) {
        float dn = den[j].x + den[j].y;
        float nm[O];
#pragma unroll
        for (int o = 0; o < O; ++o) nm[o] = num[j][o].x + num[j][o].y;
#pragma unroll
        for (int off = 4; off < 64; off <<= 1) {
            dn += __shfl_xor(dn, off, 64);
#pragma unroll
            for (int o = 0; o < O; ++o) nm[o] += __shfl_xor(nm[o], off, 64);
        }
        if (sl == 0) {
            const float inv = 1.0f / dn;
            float v[O];
#pragma unroll
            for (int o = 0; o < O; ++o) {
                const float t = nm[o] * inv;
                v[o] = (t > 0.0f) ? t : (__expf(t) - 1.0f);   // ELU(alpha=1)
            }
            const int row = rowbase + rg + 4 * j;
            float* po = out + ((size_t)b * N + row) * (H * O) + h * O;
            if constexpr (O == 2) {
                *(float2*)po = make_float2(v[0], v[1]);
            } else {
                *(float4*)po = make_float4(v[0], v[1], v[2], v[3]);
            }
        }
    }
}

extern "C" void kernel_launch(void* const* d_in, const int* in_sizes, int n_in,
                              void* d_out, int out_size, void* d_ws, size_t ws_size,
                              hipStream_t stream) {
    const float* x  = (const float*)d_in[0];  // (32,1024,4)
    const float* W1 = (const float*)d_in[1];  // (3,4,2)
    const float* a1 = (const float*)d_in[2];  // (3,4,1)
    const float* W2 = (const float*)d_in[3];  // (1,6,4)
    const float* a2 = (const float*)d_in[4];  // (1,8,1)

    float* h1 = (float*)d_ws;     // (32,1024,6) fp32 = 768 KiB scratch
    float* y  = (float*)d_out;    // (32,1024,4) fp32

    constexpr int B = 32;
    // Layer 1: H=3,F=4,O=2, RPB=64 -> 1536 blocks (6/CU, LDS 16 KB), b-minor
    gat_layer_kernel<4, 2, 3, 64, 6><<<B * 3 * 16, 256, 0, stream>>>(x, W1, a1, h1);
    // Layer 2: H=1,F=6,O=4, RPB=32 -> 1024 blocks (4/CU, LDS 24 KB), b-minor
    gat_layer_kernel<6, 4, 1, 32, 4><<<B * 1 * 32, 256, 0, stream>>>(h1, W2, a2, y);
}